// Round 9
// baseline (120.916 us; speedup 1.0000x reference)
//
#include <hip/hip_runtime.h>
#include <cstddef>

#define NCOLS 985
#define TROWS 4                    // rows per LDS tile
#define TILEF (TROWS * NCOLS)      // 3940 floats per tile
#define NT4   (TILEF / 4)          // 985 float4 units (3940 % 4 == 0)
#define GSTR  176                  // per-wave G slots

__global__ __launch_bounds__(256) void sindy_kernel(const float* __restrict__ z,
                                                    const float* __restrict__ dz,
                                                    float* __restrict__ out, int batch,
                                                    int ntiles) {
  __shared__ unsigned short mtab[1024];   // col -> a | b<<8 (G indices)
  __shared__ unsigned short ptab[136];    // pair p -> i | j<<4
  __shared__ float G[4][GSTR];            // per-wave factor array
  __shared__ alignas(16) float rowbuf[TILEF];   // 15760 B staging tile

  const int tid = threadIdx.x;

  // ---- build static tables (once per block) ----
  for (int e = tid; e < 1024; e += 256) {
    int a, b;
    if (e < 153)       { a = (e == 0) ? 0 : e; b = 0; }
    else if (e < 969)  {
      int t = e - 153, i = 0;
      for (;;) { int c = (16 - i) * (17 - i) / 2; if (t < c) break; t -= c; ++i; }
      int j = i; while (t >= 16 - j) { t -= 16 - j; ++j; }
      int k = j + t;
      int p = i * 16 - i * (i - 1) / 2 + (j - i);
      a = 17 + p; b = 1 + k;
    }
    else if (e < 985)  { a = 153 + (e - 969); b = 0; }
    else               { a = 169; b = 169; }
    mtab[e] = (unsigned short)(a | (b << 8));
  }
  for (int e = tid; e < 136; e += 256) {
    int p = e, i = 0; while (p >= 16 - i) { p -= 16 - i; ++i; }
    ptab[e] = (unsigned short)(i | ((i + p) << 4));
  }
  __syncthreads();

  const int w = tid >> 6, l = tid & 63;

  // per-lane static table entries in VGPRs (fixed across rows)
  unsigned short mt[16];
  #pragma unroll
  for (int wd = 0; wd < 16; ++wd) mt[wd] = mtab[wd * 64 + l];
  const unsigned pe0 = ptab[l];
  const unsigned pe1 = ptab[64 + l];
  const unsigned pe2 = ptab[(128 + l < 136) ? (128 + l) : 135];

  float* Gw = G[w];

  for (int tile = blockIdx.x; tile < ntiles; tile += gridDim.x) {
    const int trow0 = tile * TROWS;
    const int row   = trow0 + w;          // wave w computes tile-local row w
    const int nrows = (batch - trow0 < TROWS) ? (batch - trow0) : TROWS;

    // ---- compute phase: one row per wave into rowbuf ----
    if (row < batch) {
      // stage G[0..16] (1, zc) + zero pad 169..175
      float gval = 0.f;
      if (l == 0)       gval = 1.0f;
      else if (l < 9)   gval = z [(size_t)row * 8 + (l - 1)];
      else if (l < 17)  gval = dz[(size_t)row * 8 + (l - 9)];
      const int gaddr = (l < 17) ? l : (152 + l);
      if (l < 24) Gw[gaddr] = gval;

      const float sv = __shfl(gval, l + 1);
      if (l < 16) Gw[153 + l] = __sinf(sv);
      __builtin_amdgcn_sched_barrier(0);    // G base writes before pair gathers

      // pairs G[17..152] (same-wave DS is in-order)
      {
        float a0 = Gw[1 + (pe0 & 15)], b0 = Gw[1 + (pe0 >> 4)];
        Gw[17 + l] = a0 * b0;
        float a1 = Gw[1 + (pe1 & 15)], b1 = Gw[1 + (pe1 >> 4)];
        Gw[17 + 64 + l] = a1 * b1;
        if (l < 8) {
          float a2 = Gw[1 + (pe2 & 15)], b2 = Gw[1 + (pe2 >> 4)];
          Gw[17 + 128 + l] = a2 * b2;
        }
      }
      __builtin_amdgcn_sched_barrier(0);    // pair writes before main gathers

      // main: 16 windows x 64 cols -> rowbuf (2 gathers + mul + ds_write)
      float* rb = rowbuf + w * NCOLS;
      #pragma unroll
      for (int wd = 0; wd < 16; ++wd) {
        const unsigned e = mt[wd];
        const float v = Gw[e & 255] * Gw[e >> 8];
        if (wd < 15)              rb[wd * 64 + l] = v;
        else if (l < NCOLS - 960) rb[960 + l] = v;
      }
    }
    __syncthreads();   // tile fully staged

    // ---- drain phase: flat, 16B-aligned, single-pass float4 stores ----
    if (nrows == TROWS) {
      float4* __restrict__ dst = (float4*)(out + (size_t)tile * TILEF);
      const float4* srcq = (const float4*)rowbuf;
      #pragma unroll 4
      for (int u = tid; u < NT4; u += 256) {
        dst[u] = srcq[u];
      }
    } else {
      const int nel = nrows * NCOLS;
      float* __restrict__ dst = out + (size_t)tile * TILEF;
      for (int u = tid; u < nel; u += 256) dst[u] = rowbuf[u];
    }
    __syncthreads();   // drain done before next tile's compute overwrites rowbuf
  }
}

extern "C" void kernel_launch(void* const* d_in, const int* in_sizes, int n_in,
                              void* d_out, int out_size, void* d_ws, size_t ws_size,
                              hipStream_t stream) {
  const float* z  = (const float*)d_in[0];
  const float* dz = (const float*)d_in[1];
  float* out = (float*)d_out;
  const int batch = in_sizes[0] / 8;   // LATENT_DIM = 8

  const int ntiles = (batch + TROWS - 1) / TROWS;   // 32768
  const int blocks = 1792;                           // 7 blocks/CU resident
  sindy_kernel<<<blocks, 256, 0, stream>>>(z, dz, out, batch, ntiles);
}